// Round 13
// baseline (103.403 us; speedup 1.0000x reference)
//
#include <hip/hip_runtime.h>
#include <hip/hip_bf16.h>

typedef short bf16x8 __attribute__((ext_vector_type(8)));
typedef float f32x4  __attribute__((ext_vector_type(4)));
typedef unsigned short u16;

#define Bc    16
#define Vc    20
#define MFc   32
#define MTc   8
#define NPc   4
#define Kc    3
#define Rc    12
#define Dc    128
#define NOUTc 64

#define TOTAL_UNITS (Bc * Vc * MTc * MFc)   // 81920 ; u = bv*256 + f*8 + t
#define XPU 144                             // rel floats per unit
#define UPB 16                              // units per block (one 16-unit batch)
#define NBLOCKS (TOTAL_UNITS / UPB)         // 5120
#define ZLD 520                             // zp row length (u16): 512 + pad

// d_ws tables (bf16 bits):
//   diagB[128 d][32 r]  @ 0     : W_rel diagonal, r>=12 zeroed (P1 B-operand)
//   Wb   [64 n][128 d]  @ 4096  : out_w transposed (P2 B-operand)
__global__ void setup_tabs(const float* __restrict__ W_rel,
                           const float* __restrict__ out_w,
                           u16* __restrict__ ws) {
    const int i = blockIdx.x * 256 + threadIdx.x;
    if (i < 128 * 32) {
        const int d = i >> 5, r = i & 31;
        const float v = (r < Rc) ? W_rel[(r * Dc + d) * Dc + d] : 0.f;
        union { __hip_bfloat16 h; u16 u; } cv; cv.h = __float2bfloat16(v);
        ws[i] = cv.u;
    } else if (i < 128 * 32 + 64 * 128) {
        const int j = i - 128 * 32;
        const int n = j >> 7, d = j & 127;
        union { __hip_bfloat16 h; u16 u; } cv;
        cv.h = __float2bfloat16(out_w[d * NOUTc + n]);
        ws[i] = cv.u;
    }
}

// 8 blocks/CU: LDS 16.9 KB and VGPR <= 64 must BOTH hold (64-reg occupancy cliff)
__global__ __launch_bounds__(256, 8)
void gal_kernel(const float* __restrict__ src,    // [B,V,MT,MF,D]
                const float* __restrict__ rel,    // [u][144]
                const u16*   __restrict__ diagB,  // [128][32] bf16
                const u16*   __restrict__ Wb,     // [64][128] bf16
                const float* __restrict__ attn_w, // [NOUT+D]
                const float* __restrict__ out_b,  // [NOUT]
                float* __restrict__ out)          // [B,V,NOUT]
{
    // single-buffer z tile: 16 units x (p,d) bf16 -> 16.6 KB
    __shared__ __align__(16) u16 zp[16][ZLD];

    const int tid  = threadIdx.x;
    const int lane = tid & 63;
    const int wv   = tid >> 6;
    const int c    = lane & 15;   // MFMA col / A-row index
    const int g    = lane >> 4;   // MFMA k-group / C row-group

    const int u_base = blockIdx.x * UPB;
    const int bv0    = u_base >> 8;   // whole block lies in one bv (256 % 16 == 0)

    // loop-invariant tables (L1/L2-resident; compiler may re-load freely)
    bf16x8 dgf[8];
#pragma unroll
    for (int t = 0; t < 8; ++t)
        dgf[t] = *(const bf16x8*)(diagB + (t * 16 + c) * 32 + g * 8);
    bf16x8 wbf[4];
#pragma unroll
    for (int ks = 0; ks < 4; ++ks)
        wbf[ks] = *(const bf16x8*)(Wb + (wv * 16 + c) * Dc + ks * 32 + g * 8);

    const float LOG2E = 1.4426950408889634f;
    float aw_r[8];
#pragma unroll
    for (int t = 0; t < 8; ++t)
        aw_r[t] = attn_w[NOUTc + t * 16 + c] * LOG2E;
    const float ob = out_b[wv * 16 + c];

    // P1 A-frag geometry: A-row = c -> (p = c>>2, k = c&3; k==3 pad dups k=2,
    // its C rows are never consumed). k-slice by g; r>=12 zeroed via B pad.
    const int pA  = c >> 2, klA = c & 3;
    const int rr  = pA * 3 + (klA < 3 ? klA : 2);
    const int ao0 = rr * Rc + (g & 1) * 8;
    const int ao1 = (g == 0) ? (ao0 + 4) : ao0;
    const bool vlo = (g <= 1);
    const bool vhi = (g == 0);

    const f32x4 zero4 = {0.f, 0.f, 0.f, 0.f};

    // ---- P1: each wave computes 4 units -> zp rows wv*4+j ----
    // unroll 1: serialize units to keep live ranges small (VGPR <= 64 cliff);
    // cross-unit latency hiding comes from 8 resident blocks/CU, not ILP.
#pragma unroll 1
    for (int j = 0; j < 4; ++j) {
        const int u = u_base + wv * 4 + j;
        const float* __restrict__ xu = rel + u * XPU;
        const float4 La = *(const float4*)(xu + ao0);
        const float4 Lb = *(const float4*)(xu + ao1);

        const int t8 = u & 7, f5 = (u >> 3) & 31;
        const float* __restrict__ sp = src + ((bv0 * MTc + t8) * MFc + f5) * Dc;
        float sld[8];
#pragma unroll
        for (int t = 0; t < 8; ++t) sld[t] = sp[t * 16 + c];

        // A-fragment: fp32 -> bf16 pairs, zero padded k-slots
        union { __hip_bfloat162 h; unsigned int q; } q0, q1, q2, q3;
        q0.h = __float22bfloat162_rn(make_float2(La.x, La.y));
        q1.h = __float22bfloat162_rn(make_float2(La.z, La.w));
        q2.h = __float22bfloat162_rn(make_float2(Lb.x, Lb.y));
        q3.h = __float22bfloat162_rn(make_float2(Lb.z, Lb.w));
        union { bf16x8 v; unsigned int q[4]; } af;
        af.q[0] = vlo ? q0.q : 0u;
        af.q[1] = vlo ? q1.q : 0u;
        af.q[2] = vhi ? q2.q : 0u;
        af.q[3] = vhi ? q3.q : 0u;

        // 8 MFMAs over d-tiles (C[pk, d]; lane holds p=g, k=reg)
        f32x4 pa[8];
#pragma unroll
        for (int t = 0; t < 8; ++t)
            pa[t] = __builtin_amdgcn_mfma_f32_16x16x32_bf16(af.v, dgf[t], zero4, 0, 0, 0);

        // k-product (regs 0..2 of own p=g) + logit partial
        float w[8], lp = 0.f;
#pragma unroll
        for (int t = 0; t < 8; ++t) {
            w[t] = pa[t][0] * pa[t][1] * pa[t][2];
            lp = fmaf(w[t], sld[t] * aw_r[t], lp);
        }
        lp += __shfl_xor(lp, 1);
        lp += __shfl_xor(lp, 2);
        lp += __shfl_xor(lp, 4);
        lp += __shfl_xor(lp, 8);
        const float lA = lp;                    // logit of p = g
        const float lB = __shfl_xor(lp, 16);    // p = g^1
        const float lC = __shfl_xor(lp, 32);    // p = g^2
        const float lD = __shfl_xor(lB, 32);    // p = g^3

        // softmax over 4 paths, log2 domain (uniform terms cancel)
        const float m   = fmaxf(fmaxf(lA, lB), fmaxf(lC, lD));
        const float eS  = exp2f(lA - m);
        const float sum = eS + exp2f(lB - m) + exp2f(lC - m) + exp2f(lD - m);
        const float aS  = eS * __builtin_amdgcn_rcpf(sum);  // own path weight

        // zp store: (p=g, d=t*16+c)
        u16* zr = &zp[wv * 4 + j][g * 128 + c];
#pragma unroll
        for (int t = 0; t < 8; ++t) {
            union { __hip_bfloat16 h; u16 u; } cv;
            cv.h = __float2bfloat16(aS * sld[t] * w[t]);
            zr[t * 16] = cv.u;
        }
    }

    __syncthreads();   // zp complete

    // ---- P2: [16 units x K=512] @ Wb -> C[units, n]; wave = N-tile wv ----
    f32x4 ca = zero4, cb = zero4;
#pragma unroll
    for (int p = 0; p < 2; ++p)
#pragma unroll
        for (int ks = 0; ks < 4; ++ks) {
            const bf16x8 az = *(const bf16x8*)(&zp[c][p * 128 + ks * 32 + g * 8]);
            ca = __builtin_amdgcn_mfma_f32_16x16x32_bf16(az, wbf[ks], ca, 0, 0, 0);
        }
#pragma unroll
    for (int p = 2; p < 4; ++p)
#pragma unroll
        for (int ks = 0; ks < 4; ++ks) {
            const bf16x8 az = *(const bf16x8*)(&zp[c][p * 128 + ks * 32 + g * 8]);
            cb = __builtin_amdgcn_mfma_f32_16x16x32_bf16(az, wbf[ks], cb, 0, 0, 0);
        }

    // epilogue: bias + relu per unit-row (rows g*4+i), sum my 4 rows
    float acc = 0.f;
#pragma unroll
    for (int i = 0; i < 4; ++i)
        acc += fmaxf(ca[i] + cb[i] + ob, 0.f);

    // reduce over row-groups (g) and emit: wave owns distinct n-range
    acc += __shfl_xor(acc, 16);
    acc += __shfl_xor(acc, 32);
    if (lane < 16)
        atomicAdd(&out[bv0 * NOUTc + wv * 16 + lane], acc);
}

extern "C" void kernel_launch(void* const* d_in, const int* in_sizes, int n_in,
                              void* d_out, int out_size, void* d_ws, size_t ws_size,
                              hipStream_t stream) {
    const float* src    = (const float*)d_in[0];  // source_embed
    const float* rel    = (const float*)d_in[1];  // rel_index
    // d_in[2] = s        (cancels in softmax)
    const float* W_rel  = (const float*)d_in[3];
    const float* attn_w = (const float*)d_in[4];
    // d_in[5] = attn_b   (cancels in softmax)
    const float* out_w  = (const float*)d_in[6];
    const float* out_b  = (const float*)d_in[7];
    float* out  = (float*)d_out;
    u16*   tabs = (u16*)d_ws;                     // 24 KB of bf16 tables

    hipMemsetAsync(out, 0, (size_t)out_size * sizeof(float), stream);
    setup_tabs<<<48, 256, 0, stream>>>(W_rel, out_w, tabs);
    gal_kernel<<<NBLOCKS, 256, 0, stream>>>(src, rel, tabs, tabs + 128 * 32,
                                            attn_w, out_b, out);
}

// Round 14
// 53.242 us; speedup vs baseline: 1.9421x; 1.9421x over previous
//
#include <hip/hip_runtime.h>
#include <hip/hip_bf16.h>

typedef short bf16x8 __attribute__((ext_vector_type(8)));
typedef float f32x4  __attribute__((ext_vector_type(4)));
typedef unsigned short u16;

#define Bc    16
#define Vc    20
#define MFc   32
#define MTc   8
#define NPc   4
#define Kc    3
#define Rc    12
#define Dc    128
#define NOUTc 64

#define TOTAL_UNITS (Bc * Vc * MTc * MFc)   // 81920 ; u = bv*256 + f*8 + t
#define XPU 144                             // rel floats per unit
#define UPB 16                              // units per block (one 16-unit batch)
#define NBLOCKS (TOTAL_UNITS / UPB)         // 5120
#define ZLD 520                             // zp row length (u16): 512 + pad

// d_ws tables (bf16 bits):
//   diagB[128 d][32 r]  @ 0     : W_rel diagonal, r>=12 zeroed (P1 B-operand)
//   Wb   [64 n][128 d]  @ 4096  : out_w transposed (P2 B-operand)
__global__ void setup_tabs(const float* __restrict__ W_rel,
                           const float* __restrict__ out_w,
                           u16* __restrict__ ws) {
    const int i = blockIdx.x * 256 + threadIdx.x;
    if (i < 128 * 32) {
        const int d = i >> 5, r = i & 31;
        const float v = (r < Rc) ? W_rel[(r * Dc + d) * Dc + d] : 0.f;
        union { __hip_bfloat16 h; u16 u; } cv; cv.h = __float2bfloat16(v);
        ws[i] = cv.u;
    } else if (i < 128 * 32 + 64 * 128) {
        const int j = i - 128 * 32;
        const int n = j >> 7, d = j & 127;
        union { __hip_bfloat16 h; u16 u; } cv;
        cv.h = __float2bfloat16(out_w[d * NOUTc + n]);
        ws[i] = cv.u;
    }
}

// NOTE: no min-waves arg — measured twice (R2, R13) that it forces the
// allocator to a tiny VGPR target and spills. VGPR is controlled by the
// serialized j-loop (unroll 1) keeping live ranges small.
__global__ __launch_bounds__(256)
void gal_kernel(const float* __restrict__ src,    // [B,V,MT,MF,D]
                const float* __restrict__ rel,    // [u][144]
                const u16*   __restrict__ diagB,  // [128][32] bf16
                const u16*   __restrict__ Wb,     // [64][128] bf16
                const float* __restrict__ attn_w, // [NOUT+D]
                const float* __restrict__ out_b,  // [NOUT]
                float* __restrict__ out)          // [B,V,NOUT]
{
    // single-buffer z tile: 16 units x (p,d) bf16 -> 16.6 KB => 8 blocks/CU
    __shared__ __align__(16) u16 zp[16][ZLD];

    const int tid  = threadIdx.x;
    const int lane = tid & 63;
    const int wv   = tid >> 6;
    const int c    = lane & 15;   // MFMA col / A-row index
    const int g    = lane >> 4;   // MFMA k-group / C row-group

    const int u_base = blockIdx.x * UPB;
    const int bv0    = u_base >> 8;   // whole block lies in one bv (256 % 16 == 0)

    // loop-invariant tables (L1/L2-resident; compiler may re-load freely)
    bf16x8 dgf[8];
#pragma unroll
    for (int t = 0; t < 8; ++t)
        dgf[t] = *(const bf16x8*)(diagB + (t * 16 + c) * 32 + g * 8);
    bf16x8 wbf[4];
#pragma unroll
    for (int ks = 0; ks < 4; ++ks)
        wbf[ks] = *(const bf16x8*)(Wb + (wv * 16 + c) * Dc + ks * 32 + g * 8);

    const float LOG2E = 1.4426950408889634f;
    float aw_r[8];
#pragma unroll
    for (int t = 0; t < 8; ++t)
        aw_r[t] = attn_w[NOUTc + t * 16 + c] * LOG2E;
    const float ob = out_b[wv * 16 + c];

    // P1 A-frag geometry: A-row = c -> (p = c>>2, k = c&3; k==3 pad dups k=2,
    // its C rows are never consumed). k-slice by g; r>=12 zeroed via B pad.
    const int pA  = c >> 2, klA = c & 3;
    const int rr  = pA * 3 + (klA < 3 ? klA : 2);
    const int ao0 = rr * Rc + (g & 1) * 8;
    const int ao1 = (g == 0) ? (ao0 + 4) : ao0;
    const bool vlo = (g <= 1);
    const bool vhi = (g == 0);

    const f32x4 zero4 = {0.f, 0.f, 0.f, 0.f};

    // ---- P1: each wave computes 4 units -> zp rows wv*4+j ----
    // unroll 1: serialize units; latency hiding via 8 resident blocks/CU.
#pragma unroll 1
    for (int j = 0; j < 4; ++j) {
        const int u = u_base + wv * 4 + j;
        const float* __restrict__ xu = rel + u * XPU;
        const float4 La = *(const float4*)(xu + ao0);
        const float4 Lb = *(const float4*)(xu + ao1);

        const int t8 = u & 7, f5 = (u >> 3) & 31;
        const float* __restrict__ sp = src + ((bv0 * MTc + t8) * MFc + f5) * Dc;
        float sld[8];
#pragma unroll
        for (int t = 0; t < 8; ++t) sld[t] = sp[t * 16 + c];

        // A-fragment: fp32 -> bf16 pairs, zero padded k-slots
        union { __hip_bfloat162 h; unsigned int q; } q0, q1, q2, q3;
        q0.h = __float22bfloat162_rn(make_float2(La.x, La.y));
        q1.h = __float22bfloat162_rn(make_float2(La.z, La.w));
        q2.h = __float22bfloat162_rn(make_float2(Lb.x, Lb.y));
        q3.h = __float22bfloat162_rn(make_float2(Lb.z, Lb.w));
        union { bf16x8 v; unsigned int q[4]; } af;
        af.q[0] = vlo ? q0.q : 0u;
        af.q[1] = vlo ? q1.q : 0u;
        af.q[2] = vhi ? q2.q : 0u;
        af.q[3] = vhi ? q3.q : 0u;

        // 8 MFMAs over d-tiles (C[pk, d]; lane holds p=g, k=reg)
        f32x4 pa[8];
#pragma unroll
        for (int t = 0; t < 8; ++t)
            pa[t] = __builtin_amdgcn_mfma_f32_16x16x32_bf16(af.v, dgf[t], zero4, 0, 0, 0);

        // k-product (regs 0..2 of own p=g) + logit partial
        float w[8], lp = 0.f;
#pragma unroll
        for (int t = 0; t < 8; ++t) {
            w[t] = pa[t][0] * pa[t][1] * pa[t][2];
            lp = fmaf(w[t], sld[t] * aw_r[t], lp);
        }
        lp += __shfl_xor(lp, 1);
        lp += __shfl_xor(lp, 2);
        lp += __shfl_xor(lp, 4);
        lp += __shfl_xor(lp, 8);
        const float lA = lp;                    // logit of p = g
        const float lB = __shfl_xor(lp, 16);    // p = g^1
        const float lC = __shfl_xor(lp, 32);    // p = g^2
        const float lD = __shfl_xor(lB, 32);    // p = g^3

        // softmax over 4 paths, log2 domain (uniform terms cancel)
        const float m   = fmaxf(fmaxf(lA, lB), fmaxf(lC, lD));
        const float eS  = exp2f(lA - m);
        const float sum = eS + exp2f(lB - m) + exp2f(lC - m) + exp2f(lD - m);
        const float aS  = eS * __builtin_amdgcn_rcpf(sum);  // own path weight

        // zp store: (p=g, d=t*16+c)
        u16* zr = &zp[wv * 4 + j][g * 128 + c];
#pragma unroll
        for (int t = 0; t < 8; ++t) {
            union { __hip_bfloat16 h; u16 u; } cv;
            cv.h = __float2bfloat16(aS * sld[t] * w[t]);
            zr[t * 16] = cv.u;
        }
    }

    __syncthreads();   // zp complete

    // ---- P2: [16 units x K=512] @ Wb -> C[units, n]; wave = N-tile wv ----
    f32x4 ca = zero4, cb = zero4;
#pragma unroll
    for (int p = 0; p < 2; ++p)
#pragma unroll
        for (int ks = 0; ks < 4; ++ks) {
            const bf16x8 az = *(const bf16x8*)(&zp[c][p * 128 + ks * 32 + g * 8]);
            ca = __builtin_amdgcn_mfma_f32_16x16x32_bf16(az, wbf[ks], ca, 0, 0, 0);
        }
#pragma unroll
    for (int p = 2; p < 4; ++p)
#pragma unroll
        for (int ks = 0; ks < 4; ++ks) {
            const bf16x8 az = *(const bf16x8*)(&zp[c][p * 128 + ks * 32 + g * 8]);
            cb = __builtin_amdgcn_mfma_f32_16x16x32_bf16(az, wbf[ks], cb, 0, 0, 0);
        }

    // epilogue: bias + relu per unit-row (rows g*4+i), sum my 4 rows
    float acc = 0.f;
#pragma unroll
    for (int i = 0; i < 4; ++i)
        acc += fmaxf(ca[i] + cb[i] + ob, 0.f);

    // reduce over row-groups (g) and emit: wave owns distinct n-range
    acc += __shfl_xor(acc, 16);
    acc += __shfl_xor(acc, 32);
    if (lane < 16)
        atomicAdd(&out[bv0 * NOUTc + wv * 16 + lane], acc);
}

extern "C" void kernel_launch(void* const* d_in, const int* in_sizes, int n_in,
                              void* d_out, int out_size, void* d_ws, size_t ws_size,
                              hipStream_t stream) {
    const float* src    = (const float*)d_in[0];  // source_embed
    const float* rel    = (const float*)d_in[1];  // rel_index
    // d_in[2] = s        (cancels in softmax)
    const float* W_rel  = (const float*)d_in[3];
    const float* attn_w = (const float*)d_in[4];
    // d_in[5] = attn_b   (cancels in softmax)
    const float* out_w  = (const float*)d_in[6];
    const float* out_b  = (const float*)d_in[7];
    float* out  = (float*)d_out;
    u16*   tabs = (u16*)d_ws;                     // 24 KB of bf16 tables

    hipMemsetAsync(out, 0, (size_t)out_size * sizeof(float), stream);
    setup_tabs<<<48, 256, 0, stream>>>(W_rel, out_w, tabs);
    gal_kernel<<<NBLOCKS, 256, 0, stream>>>(src, rel, tabs, tabs + 128 * 32,
                                            attn_w, out_b, out);
}

// Round 15
// 47.179 us; speedup vs baseline: 2.1917x; 1.1285x over previous
//
#include <hip/hip_runtime.h>
#include <hip/hip_bf16.h>

typedef short bf16x8 __attribute__((ext_vector_type(8)));
typedef float f32x4  __attribute__((ext_vector_type(4)));
typedef unsigned short u16;

#define Bc    16
#define Vc    20
#define MFc   32
#define MTc   8
#define NPc   4
#define Kc    3
#define Rc    12
#define Dc    128
#define NOUTc 64

#define TOTAL_UNITS (Bc * Vc * MTc * MFc)   // 81920 ; u = bv*256 + f*8 + t
#define XPU 144                             // rel floats per unit
#define NBLOCKS 1024                        // 4 blocks/CU
#define UPB 80                              // units per block
#define NBATCH 5                            // 16-unit batches per block
#define ZLD 520                             // zp row length (u16): 512 + pad

// d_ws tables (bf16 bits):
//   diagB[128 d][32 r]  @ 0     : W_rel diagonal, r>=12 zeroed (P1 B-operand)
//   Wb   [64 n][128 d]  @ 4096  : out_w transposed (P2 B-operand)
__global__ void setup_tabs(const float* __restrict__ W_rel,
                           const float* __restrict__ out_w,
                           u16* __restrict__ ws) {
    const int i = blockIdx.x * 256 + threadIdx.x;
    if (i < 128 * 32) {
        const int d = i >> 5, r = i & 31;
        const float v = (r < Rc) ? W_rel[(r * Dc + d) * Dc + d] : 0.f;
        union { __hip_bfloat16 h; u16 u; } cv; cv.h = __float2bfloat16(v);
        ws[i] = cv.u;
    } else if (i < 128 * 32 + 64 * 128) {
        const int j = i - 128 * 32;
        const int n = j >> 7, d = j & 127;
        union { __hip_bfloat16 h; u16 u; } cv;
        cv.h = __float2bfloat16(out_w[d * NOUTc + n]);
        ws[i] = cv.u;
    }
}

// NOTE: plain launch_bounds only — the min-waves arg forced spill disasters
// twice (R2, R13). VGPR stays <=64 via short live ranges, not allocator clamps.
__global__ __launch_bounds__(256)
void gal_kernel(const float* __restrict__ src,    // [B,V,MT,MF,D]
                const float* __restrict__ rel,    // [u][144]
                const u16*   __restrict__ diagB,  // [128][32] bf16
                const u16*   __restrict__ Wb,     // [64][128] bf16
                const float* __restrict__ attn_w, // [NOUT+D]
                const float* __restrict__ out_b,  // [NOUT]
                float* __restrict__ out)          // [B,V,NOUT]
{
    // zp[buf][unit-in-batch][(p,d) XOR-tiled] bf16 : K=512 for P2
    __shared__ __align__(16) u16 zp[2][16][ZLD];   // 33.3 KB

    const int tid  = threadIdx.x;
    const int lane = tid & 63;
    const int wv   = tid >> 6;
    const int c    = lane & 15;   // MFMA col / A-row index
    const int g    = lane >> 4;   // MFMA k-group / C row-group

    const int u_base = blockIdx.x * UPB;
    const int bv0    = u_base >> 8;

    // loop-invariant tables (L1-resident; compiler may re-load as needed)
    bf16x8 dgf[8];
#pragma unroll
    for (int t = 0; t < 8; ++t)
        dgf[t] = *(const bf16x8*)(diagB + (t * 16 + c) * 32 + g * 8);
    bf16x8 wbf[4];
#pragma unroll
    for (int ks = 0; ks < 4; ++ks)
        wbf[ks] = *(const bf16x8*)(Wb + (wv * 16 + c) * Dc + ks * 32 + g * 8);

    const float LOG2E = 1.4426950408889634f;
    float aw_r[8];
#pragma unroll
    for (int t = 0; t < 8; ++t)
        aw_r[t] = attn_w[NOUTc + t * 16 + c] * LOG2E;
    const float ob = out_b[wv * 16 + c];

    // P1 A-frag geometry: A-row = c -> (p = c>>2, k = c&3; k==3 pad dups k=2,
    // its C rows are never consumed). k-slice by g; r>=12 zeroed via B pad.
    const int pA  = c >> 2, klA = c & 3;
    const int rr  = pA * 3 + (klA < 3 ? klA : 2);
    const int ao0 = rr * Rc + (g & 1) * 8;
    const int ao1 = (g == 0) ? (ao0 + 4) : ao0;
    const bool vlo = (g <= 1);
    const bool vhi = (g == 0);

    const f32x4 zero4 = {0.f, 0.f, 0.f, 0.f};
    float accA = 0.f, accB = 0.f;

    // store/read swizzle helpers: z[p][d] lives at column
    //   p*128 + ((d>>4)^p)*16 + (d&15)
    // store side: p=g, d=t*16+c -> col = g*128 + c + ((t*16)^(g*16))
    const int sbase = g * 128 + c;
    const int gx16  = g * 16;
    const int gh    = g >> 1, gl = (g & 1) * 8;

    for (int b = 0; b < NBATCH; ++b) {
        const int X   = b & 1;
        const int ub0 = u_base + b * 16;

        // ---- P1: each wave computes 4 units -> zp rows wv*4+j ----
        for (int j = 0; j < 4; ++j) {
            const int u = ub0 + wv * 4 + j;
            const float* __restrict__ xu = rel + u * XPU;
            const float4 La = *(const float4*)(xu + ao0);
            const float4 Lb = *(const float4*)(xu + ao1);

            const int t8 = u & 7, f5 = (u >> 3) & 31, ubv = u >> 8;
            const float* __restrict__ sp = src + ((ubv * MTc + t8) * MFc + f5) * Dc;
            float sld[8];
#pragma unroll
            for (int t = 0; t < 8; ++t) sld[t] = sp[t * 16 + c];

            // A-fragment: fp32 -> bf16 pairs, zero padded k-slots
            union { __hip_bfloat162 h; unsigned int q; } q0, q1, q2, q3;
            q0.h = __float22bfloat162_rn(make_float2(La.x, La.y));
            q1.h = __float22bfloat162_rn(make_float2(La.z, La.w));
            q2.h = __float22bfloat162_rn(make_float2(Lb.x, Lb.y));
            q3.h = __float22bfloat162_rn(make_float2(Lb.z, Lb.w));
            union { bf16x8 v; unsigned int q[4]; } af;
            af.q[0] = vlo ? q0.q : 0u;
            af.q[1] = vlo ? q1.q : 0u;
            af.q[2] = vhi ? q2.q : 0u;
            af.q[3] = vhi ? q3.q : 0u;

            // 8 MFMAs over d-tiles, consumed immediately (short pa live range):
            // q[t] = w_p(d) * s(d) for p = g, d = t*16 + c
            float q[8], lp = 0.f;
#pragma unroll
            for (int t = 0; t < 8; ++t) {
                const f32x4 pa =
                    __builtin_amdgcn_mfma_f32_16x16x32_bf16(af.v, dgf[t], zero4, 0, 0, 0);
                q[t] = pa[0] * pa[1] * pa[2] * sld[t];
                lp = fmaf(q[t], aw_r[t], lp);
            }
            lp += __shfl_xor(lp, 1);
            lp += __shfl_xor(lp, 2);
            lp += __shfl_xor(lp, 4);
            lp += __shfl_xor(lp, 8);
            const float lA = lp;                    // logit of p = g
            const float lB = __shfl_xor(lp, 16);    // p = g^1
            const float lC = __shfl_xor(lp, 32);    // p = g^2
            const float lD = __shfl_xor(lB, 32);    // p = g^3

            // softmax over 4 paths, log2 domain (uniform terms cancel)
            const float m   = fmaxf(fmaxf(lA, lB), fmaxf(lC, lD));
            const float eS  = exp2f(lA - m);
            const float sum = eS + exp2f(lB - m) + exp2f(lC - m) + exp2f(lD - m);
            const float aS  = eS * __builtin_amdgcn_rcpf(sum);  // own path weight

            // zp store, XOR-tiled: 4 g-groups land on disjoint bank octets
            u16* zrow = &zp[X][wv * 4 + j][0];
#pragma unroll
            for (int t = 0; t < 8; ++t) {
                union { __hip_bfloat16 h; u16 u; } cv;
                cv.h = __float2bfloat16(aS * q[t]);
                zrow[sbase + ((t * 16) ^ gx16)] = cv.u;
            }
        }

        __syncthreads();   // zp[X] complete; zp[X^1] untouched by this batch

        // ---- P2: [16 units x K=512] @ Wb -> C[units, n]; wave = N-tile wv ----
        f32x4 ca = zero4, cb = zero4;
#pragma unroll
        for (int p = 0; p < 2; ++p)
#pragma unroll
            for (int ks = 0; ks < 4; ++ks) {
                const int tile = (2 * ks + gh) ^ p;
                const bf16x8 az = *(const bf16x8*)(&zp[X][c][p * 128 + tile * 16 + gl]);
                ca = __builtin_amdgcn_mfma_f32_16x16x32_bf16(az, wbf[ks], ca, 0, 0, 0);
            }
#pragma unroll
        for (int p = 2; p < 4; ++p)
#pragma unroll
            for (int ks = 0; ks < 4; ++ks) {
                const int tile = (2 * ks + gh) ^ p;
                const bf16x8 az = *(const bf16x8*)(&zp[X][c][p * 128 + tile * 16 + gl]);
                cb = __builtin_amdgcn_mfma_f32_16x16x32_bf16(az, wbf[ks], cb, 0, 0, 0);
            }

        // epilogue: bias + relu per unit-row (rows g*4+i), sum my 4 rows
        float su = 0.f;
#pragma unroll
        for (int i = 0; i < 4; ++i)
            su += fmaxf(ca[i] + cb[i] + ob, 0.f);
        if ((ub0 >> 8) == bv0) accA += su; else accB += su;
        // 16-unit batches never straddle a bv boundary (256 % 16 == 0)
    }

    // reduce over row-groups (g) and emit: wave owns distinct n-range
    accA += __shfl_xor(accA, 16); accA += __shfl_xor(accA, 32);
    accB += __shfl_xor(accB, 16); accB += __shfl_xor(accB, 32);
    if (lane < 16) {
        atomicAdd(&out[bv0 * NOUTc + wv * 16 + lane], accA);
        const int bvL = (u_base + UPB - 1) >> 8;
        if (bvL != bv0) atomicAdd(&out[bvL * NOUTc + wv * 16 + lane], accB);
    }
}

extern "C" void kernel_launch(void* const* d_in, const int* in_sizes, int n_in,
                              void* d_out, int out_size, void* d_ws, size_t ws_size,
                              hipStream_t stream) {
    const float* src    = (const float*)d_in[0];  // source_embed
    const float* rel    = (const float*)d_in[1];  // rel_index
    // d_in[2] = s        (cancels in softmax)
    const float* W_rel  = (const float*)d_in[3];
    const float* attn_w = (const float*)d_in[4];
    // d_in[5] = attn_b   (cancels in softmax)
    const float* out_w  = (const float*)d_in[6];
    const float* out_b  = (const float*)d_in[7];
    float* out  = (float*)d_out;
    u16*   tabs = (u16*)d_ws;                     // 24 KB of bf16 tables

    hipMemsetAsync(out, 0, (size_t)out_size * sizeof(float), stream);
    setup_tabs<<<48, 256, 0, stream>>>(W_rel, out_w, tabs);
    gal_kernel<<<NBLOCKS, 256, 0, stream>>>(src, rel, tabs, tabs + 128 * 32,
                                            attn_w, out_b, out);
}

// Round 17
// 42.165 us; speedup vs baseline: 2.4523x; 1.1189x over previous
//
#include <hip/hip_runtime.h>
#include <hip/hip_bf16.h>

typedef short bf16x8 __attribute__((ext_vector_type(8)));
typedef float f32x4  __attribute__((ext_vector_type(4)));
typedef float f32x16 __attribute__((ext_vector_type(16)));
typedef unsigned short u16;

#define TOTAL_UNITS 81920                   // u = bv*256 + f*8 + t
#define XPU 144                             // rel floats per unit
#define NBLOCKS 1024                        // 4 blocks/CU
#define UPB 80
#define NBATCH 5                            // 16-unit batches
#define ZLD 136                             // zs row pad (u16): banks spread 4/row

// d_ws tables (bf16 bits):
//   diagB32[128 d][16 r] @ 0     : W_rel diagonal, r>=12 zeroed (P1 B, K=16)
//   Wb     [64 n][128 d] @ 2048  : out_w transposed (P2 B, K=128)
__global__ void setup_tabs(const float* __restrict__ W_rel,
                           const float* __restrict__ out_w,
                           u16* __restrict__ ws) {
    const int i = blockIdx.x * 256 + threadIdx.x;
    if (i < 128 * 16) {
        const int d = i >> 4, r = i & 15;
        const float v = (r < 12) ? W_rel[(r * 128 + d) * 128 + d] : 0.f;
        union { __hip_bfloat16 h; u16 u; } cv; cv.h = __float2bfloat16(v);
        ws[i] = cv.u;
    } else if (i < 128 * 16 + 64 * 128) {
        const int j = i - 128 * 16;
        const int n = j >> 7, d = j & 127;
        union { __hip_bfloat16 h; u16 u; } cv;
        cv.h = __float2bfloat16(out_w[d * 64 + n]);
        ws[i] = cv.u;
    }
}

// NOTE: plain launch_bounds only — min-waves arg caused spill disasters (R2, R13).
__global__ __launch_bounds__(256)
void gal_kernel(const float* __restrict__ src,     // [B,V,MT,MF,128]
                const float* __restrict__ rel,     // [u][144]
                const u16*   __restrict__ diagB,   // [128][16] bf16
                const u16*   __restrict__ Wb,      // [64][128] bf16
                const float* __restrict__ attn_w,  // [64+128]
                const float* __restrict__ out_b,   // [64]
                float* __restrict__ out)           // [B,V,64]
{
    // p-summed z tile: 16 units x 128 d bf16, padded row, double-buffered
    __shared__ __align__(16) u16 zs[2][16][ZLD];   // 8.7 KB

    const int tid  = threadIdx.x;
    const int lane = tid & 63;
    const int wv   = tid >> 6;
    const int col0 = lane & 31;   // 32x32 MFMA col within d-tile
    const int h    = lane >> 5;   // lane half (k-group / C row-half)
    const int c    = lane & 15;   // P2 16x16 col
    const int g    = lane >> 4;   // P2 k-group

    const int u_base = blockIdx.x * UPB;
    const int bv0    = u_base >> 8;

    // P1 B-frags (diag, K=16): d = t*32+col0, r = h*8 + j (r>=12 zero)
    bf16x8 dgf[4];
#pragma unroll
    for (int t = 0; t < 4; ++t)
        dgf[t] = *(const bf16x8*)(diagB + (t * 32 + col0) * 16 + h * 8);
    // P2 B-frags (out_w, K=128)
    bf16x8 wbf[4];
#pragma unroll
    for (int ks = 0; ks < 4; ++ks)
        wbf[ks] = *(const bf16x8*)(Wb + (wv * 16 + c) * 128 + ks * 32 + g * 8);

    const float LOG2E = 1.4426950408889634f;
    float aw4[4];
#pragma unroll
    for (int t = 0; t < 4; ++t)
        aw4[t] = attn_w[64 + t * 32 + col0] * LOG2E;
    const float ob = out_b[wv * 16 + c];

    // A-row geometry: row = lane&31 -> unit uloc = row>>4, slot w4 = row&15.
    // p = perm[w4>>2], perm = {0,2,1,3} (keeps each p's 3 k-rows in one
    // lane-half's contiguous C regs); k = w4&3 (k==3 pad dups k=2, C row unused).
    const int uloc = (lane & 31) >> 4;
    const int w4   = lane & 15;
    const int sel  = w4 >> 2;
    const int p    = (sel == 1) ? 2 : ((sel == 2) ? 1 : sel);
    const int kk   = (w4 & 3) < 3 ? (w4 & 3) : 2;
    const int aoffA = uloc * XPU + p * 36 + kk * 12 + h * 8;  // r = 8h..8h+3
    const int aoffB = uloc * XPU + p * 36 + kk * 12 + 4;      // r = 4..7 (h=0)

    const f32x4  zero4  = {0.f, 0.f, 0.f, 0.f};
    const f32x16 zero16 = {0.f,0.f,0.f,0.f,0.f,0.f,0.f,0.f,
                           0.f,0.f,0.f,0.f,0.f,0.f,0.f,0.f};
    float accA = 0.f, accB = 0.f;

    for (int b = 0; b < NBATCH; ++b) {
        const int X   = b & 1;
        const int ub0 = u_base + b * 16;

        // ---- P1: 2 passes, each wave computes 2 units per pass ----
#pragma unroll 1
        for (int ps = 0; ps < 2; ++ps) {
            const int base_u = ub0 + ps * 8 + wv * 2;
            const float* __restrict__ relb = rel + base_u * XPU;
            const float4 La = *(const float4*)(relb + aoffA);
            const float4 Lb = *(const float4*)(relb + aoffB);

            const int u0 = base_u, u1 = base_u + 1;
            const int ubv = u0 >> 8;   // BUGFIX (R16): unit's OWN bv, not bv0 —
                                       // 80-unit blocks straddle bv boundaries.
                                       // u1 = u0+1 shares it (16-batches don't straddle).
            const int so0 = ((ubv * 8 + (u0 & 7)) * 32 + ((u0 >> 3) & 31)) * 128;
            const int so1 = ((ubv * 8 + (u1 & 7)) * 32 + ((u1 >> 3) & 31)) * 128;
            float s0[4], s1[4];
#pragma unroll
            for (int t = 0; t < 4; ++t) {
                s0[t] = src[so0 + t * 32 + col0];
                s1[t] = src[so1 + t * 32 + col0];
            }

            // A-frag: 8 bf16 = r-slice 8h..8h+7 of this row's rel values
            union { __hip_bfloat162 hh; unsigned int q; } q0, q1, q2, q3;
            q0.hh = __float22bfloat162_rn(make_float2(La.x, La.y));
            q1.hh = __float22bfloat162_rn(make_float2(La.z, La.w));
            q2.hh = __float22bfloat162_rn(make_float2(Lb.x, Lb.y));
            q3.hh = __float22bfloat162_rn(make_float2(Lb.z, Lb.w));
            union { bf16x8 v; unsigned int q[4]; } af;
            af.q[0] = q0.q;              // h=0: r0-1 ; h=1: r8-9
            af.q[1] = q1.q;              // h=0: r2-3 ; h=1: r10-11
            af.q[2] = h ? 0u : q2.q;     // h=1 tail r12-15 = 0 (B also zero)
            af.q[3] = h ? 0u : q3.q;

            // 4 MFMAs (one per 32-wide d-tile); k-products per C row-group:
            // gi: 0=(u0,pLo) 1=(u0,pHi) 2=(u1,pLo) 3=(u1,pHi), pLo/pHi by half
            float w[4][4];
#pragma unroll
            for (int t = 0; t < 4; ++t) {
                const f32x16 pa = __builtin_amdgcn_mfma_f32_32x32x16_bf16(
                    af.v, dgf[t], zero16, 0, 0, 0);
                w[0][t] = pa[0]  * pa[1]  * pa[2];
                w[1][t] = pa[4]  * pa[5]  * pa[6];
                w[2][t] = pa[8]  * pa[9]  * pa[10];
                w[3][t] = pa[12] * pa[13] * pa[14];
            }

            // logit partials, then one shared 5-step butterfly over 32 cols
            float lp0 = 0.f, lp1 = 0.f, lp2 = 0.f, lp3 = 0.f;
#pragma unroll
            for (int t = 0; t < 4; ++t) {
                const float sa0 = s0[t] * aw4[t];
                const float sa1 = s1[t] * aw4[t];
                lp0 = fmaf(w[0][t], sa0, lp0);
                lp1 = fmaf(w[1][t], sa0, lp1);
                lp2 = fmaf(w[2][t], sa1, lp2);
                lp3 = fmaf(w[3][t], sa1, lp3);
            }
#pragma unroll
            for (int off = 1; off <= 16; off <<= 1) {
                lp0 += __shfl_xor(lp0, off);
                lp1 += __shfl_xor(lp1, off);
                lp2 += __shfl_xor(lp2, off);
                lp3 += __shfl_xor(lp3, off);
            }
            const float o0 = __shfl_xor(lp0, 32);   // other half's paths
            const float o1 = __shfl_xor(lp1, 32);
            const float o2 = __shfl_xor(lp2, 32);
            const float o3 = __shfl_xor(lp3, 32);

            // softmax per unit over 4 paths (log2 domain; uniform terms cancel)
            const float m0 = fmaxf(fmaxf(lp0, lp1), fmaxf(o0, o1));
            const float eA0 = exp2f(lp0 - m0), eB0 = exp2f(lp1 - m0);
            const float S0  = eA0 + eB0 + exp2f(o0 - m0) + exp2f(o1 - m0);
            const float i0  = __builtin_amdgcn_rcpf(S0);
            const float a00 = eA0 * i0, a01 = eB0 * i0;

            const float m1 = fmaxf(fmaxf(lp2, lp3), fmaxf(o2, o3));
            const float eA1 = exp2f(lp2 - m1), eB1 = exp2f(lp3 - m1);
            const float S1  = eA1 + eB1 + exp2f(o2 - m1) + exp2f(o3 - m1);
            const float i1  = __builtin_amdgcn_rcpf(S1);
            const float a10 = eA1 * i1, a11 = eB1 * i1;

            // p-sum in registers (own half's 2 paths + exchanged half)
            float zA[4], zB[4];
#pragma unroll
            for (int t = 0; t < 4; ++t) {
                zA[t] = a00 * w[0][t] + a01 * w[1][t];
                zB[t] = a10 * w[2][t] + a11 * w[3][t];
            }
#pragma unroll
            for (int t = 0; t < 4; ++t) {
                zA[t] += __shfl_xor(zA[t], 32);
                zB[t] += __shfl_xor(zB[t], 32);
            }

            // store: half h stores tiles {2h, 2h+1} for both units
            const int slotA = ps * 8 + wv * 2;
#pragma unroll
            for (int tt = 0; tt < 2; ++tt) {
                const float za = h ? zA[2 + tt] : zA[tt];  // static idx select
                const float zb = h ? zB[2 + tt] : zB[tt];
                const float sa = h ? s0[2 + tt] : s0[tt];
                const float sb = h ? s1[2 + tt] : s1[tt];
                const int   dc = (2 * h + tt) * 32 + col0;
                union { __hip_bfloat16 hh; u16 u; } c0, c1;
                c0.hh = __float2bfloat16(za * sa);
                c1.hh = __float2bfloat16(zb * sb);
                zs[X][slotA][dc]     = c0.u;
                zs[X][slotA + 1][dc] = c1.u;
            }
        }

        __syncthreads();   // zs[X] complete; zs[X^1] untouched this batch

        // ---- P2: [16 units x K=128] @ Wb -> C[units, n]; wave = N-tile wv ----
        f32x4 ca = zero4;
#pragma unroll
        for (int ks = 0; ks < 4; ++ks) {
            const bf16x8 az = *(const bf16x8*)(&zs[X][c][ks * 32 + g * 8]);
            ca = __builtin_amdgcn_mfma_f32_16x16x32_bf16(az, wbf[ks], ca, 0, 0, 0);
        }
        float su = 0.f;
#pragma unroll
        for (int i = 0; i < 4; ++i)
            su += fmaxf(ca[i] + ob, 0.f);     // unit rows g*4+i
        if ((ub0 >> 8) == bv0) accA += su; else accB += su;
        // 16-unit batches never straddle a bv boundary (256 % 16 == 0)
    }

    // reduce over row-groups (g) and emit: wave owns distinct n-range
    accA += __shfl_xor(accA, 16); accA += __shfl_xor(accA, 32);
    accB += __shfl_xor(accB, 16); accB += __shfl_xor(accB, 32);
    if (lane < 16) {
        atomicAdd(&out[bv0 * 64 + wv * 16 + lane], accA);
        const int bvL = (u_base + UPB - 1) >> 8;
        if (bvL != bv0) atomicAdd(&out[bvL * 64 + wv * 16 + lane], accB);
    }
}

extern "C" void kernel_launch(void* const* d_in, const int* in_sizes, int n_in,
                              void* d_out, int out_size, void* d_ws, size_t ws_size,
                              hipStream_t stream) {
    const float* src    = (const float*)d_in[0];  // source_embed
    const float* rel    = (const float*)d_in[1];  // rel_index
    // d_in[2] = s        (cancels in softmax)
    const float* W_rel  = (const float*)d_in[3];
    const float* attn_w = (const float*)d_in[4];
    // d_in[5] = attn_b   (cancels in softmax)
    const float* out_w  = (const float*)d_in[6];
    const float* out_b  = (const float*)d_in[7];
    float* out  = (float*)d_out;
    u16*   tabs = (u16*)d_ws;                     // 20.5 KB of bf16 tables

    hipMemsetAsync(out, 0, (size_t)out_size * sizeof(float), stream);
    setup_tabs<<<40, 256, 0, stream>>>(W_rel, out_w, tabs);
    gal_kernel<<<NBLOCKS, 256, 0, stream>>>(src, rel, tabs, tabs + 128 * 16,
                                            attn_w, out_b, out);
}